// Round 1
// baseline (59.757 us; speedup 1.0000x reference)
//
#include <hip/hip_runtime.h>

// TreeMapping: DEPTH=8, N_NODES=255, N_LEAVES=256, BATCH=512.
//
// reference: comb[b,r,k] = x*right + (1-x)*left + no ; path_prob = prod_k comb.
// Masks are binary path indicators of a complete binary tree (heap layout,
// children 2i+1 / 2i+2). Non-path factors are exactly 1, so each output is a
// product of <=8 factors of x[b,a] or (1-x[b,a]) along a root-to-node path.
//   - leaf l (0..255): path bits are the binary digits of l, MSB first;
//     bit 0 -> child 2i+1, factor x[i]; bit 1 -> child 2i+2, factor 1-x[i].
//   - node idx (0..254): prefix of some leaf path; the running partial
//     product at depth d IS the node prob of the node reached at depth d.
// Output layout: d_out = leaf_probs[512][256] ++ node_probs[512][255].

#define TM_BATCH    512
#define TM_N_NODES  255
#define TM_N_LEAVES 256
#define TM_DEPTH    8

__global__ __launch_bounds__(256)
void TreeMapping_67671504715946_kernel(const float* __restrict__ x,
                                       float* __restrict__ out) {
    __shared__ float xs[TM_N_NODES];
    const int b = blockIdx.x;
    const int t = threadIdx.x;

    // Stage this batch row's x into LDS (coalesced, one barrier).
    if (t < TM_N_NODES) xs[t] = x[b * TM_N_NODES + t];
    __syncthreads();

    float* __restrict__ leaf_out = out;                               // [512][256]
    float* __restrict__ node_out = out + TM_BATCH * TM_N_LEAVES;      // [512][255]

    float p = 1.0f;
    int i = 0;
#pragma unroll
    for (int d = 0; d < TM_DEPTH; ++d) {
        // Exactly one thread per node (low (8-d) bits zero) publishes the
        // node prob, which equals the running partial product before the
        // depth-d decision. d=0: only t==0 writes node 0 with p=1.
        if ((t & ((TM_N_LEAVES >> d) - 1)) == 0) {
            node_out[b * TM_N_NODES + i] = p;
        }
        const int bit = (t >> (TM_DEPTH - 1 - d)) & 1;
        const float xv = xs[i];
        p *= bit ? (1.0f - xv) : xv;
        i = 2 * i + 1 + bit;
    }
    leaf_out[b * TM_N_LEAVES + t] = p;
}

extern "C" void kernel_launch(void* const* d_in, const int* in_sizes, int n_in,
                              void* d_out, int out_size, void* d_ws, size_t ws_size,
                              hipStream_t stream) {
    const float* x = (const float*)d_in[0];   // (512, 255) fp32
    // d_in[1..3] (right_bin/left_bin/no_bin) are implied by tree structure; unused.
    float* out = (float*)d_out;               // 512*256 + 512*255 fp32

    TreeMapping_67671504715946_kernel<<<TM_BATCH, 256, 0, stream>>>(x, out);
}

// Round 2
// 59.507 us; speedup vs baseline: 1.0042x; 1.0042x over previous
//
#include <hip/hip_runtime.h>

// TreeMapping: DEPTH=8, N_NODES=255, N_LEAVES=256, BATCH=512.
//
// Masks are binary path indicators of a complete binary tree (heap layout).
// Each output is a product of <=8 factors x[b,a] or (1-x[b,a]) along a
// root-to-node path. Leaf l's path bits are the binary digits of l (MSB
// first): bit 0 -> factor x, bit 1 -> factor 1-x.
//
// KEY CHANGE vs prev round: ancestor index has closed form
//     i_d = (1<<d) - 1 + (t >> (8-d))
// so the 8 LDS reads are INDEPENDENT (prev version chased i=2i+1+bit, a
// ~120-cyc-per-hop serial LDS chain). All 8 ds_reads now issue together.
//
// Output layout: d_out = leaf_probs[512][256] ++ node_probs[512][255].

#define TM_BATCH    512
#define TM_N_NODES  255
#define TM_N_LEAVES 256
#define TM_DEPTH    8

__global__ __launch_bounds__(256)
void TreeMapping_67671504715946_kernel(const float* __restrict__ x,
                                       float* __restrict__ out) {
    __shared__ float xs[TM_N_LEAVES];   // 255 used; 256 for alignment
    const int b = blockIdx.x;
    const int t = threadIdx.x;

    if (t < TM_N_NODES) xs[t] = x[b * TM_N_NODES + t];
    __syncthreads();

    float* __restrict__ leaf_out = out;                           // [512][256]
    float* __restrict__ node_out = out + TM_BATCH * TM_N_LEAVES;  // [512][255]

    // Gather all 8 path factors with independent LDS reads.
    float f[TM_DEPTH];
#pragma unroll
    for (int d = 0; d < TM_DEPTH; ++d) {
        const int i = (1 << d) - 1 + (t >> (TM_DEPTH - d));
        const float xv = xs[i];                       // broadcast/2-way: conflict-free
        const int bit = (t >> (TM_DEPTH - 1 - d)) & 1;
        f[d] = bit ? (1.0f - xv) : xv;                // v_cndmask, no divergence
    }

    // Prefix products; the partial BEFORE depth d is the node prob of the
    // depth-d ancestor. Exactly one lane per node (low 8-d bits zero)
    // publishes it -> each node written exactly once per row.
    float p = 1.0f;
#pragma unroll
    for (int d = 0; d < TM_DEPTH; ++d) {
        if ((t & ((TM_N_LEAVES >> d) - 1)) == 0) {
            node_out[b * TM_N_NODES + (1 << d) - 1 + (t >> (TM_DEPTH - d))] = p;
        }
        p *= f[d];
    }
    leaf_out[b * TM_N_LEAVES + t] = p;
}

extern "C" void kernel_launch(void* const* d_in, const int* in_sizes, int n_in,
                              void* d_out, int out_size, void* d_ws, size_t ws_size,
                              hipStream_t stream) {
    const float* x = (const float*)d_in[0];   // (512, 255) fp32
    // d_in[1..3] (mask matrices) are implied by the tree structure; unused.
    float* out = (float*)d_out;               // 512*256 + 512*255 fp32

    TreeMapping_67671504715946_kernel<<<TM_BATCH, 256, 0, stream>>>(x, out);
}